// Round 1
// baseline (485.238 us; speedup 1.0000x reference)
//
#include <hip/hip_runtime.h>

// EMA energy normalizer, single-pass fused: mag [B,F,T] fp32 -> (mag_norm, mag_mean)
//
// R6: fuse K1+K2 into ONE kernel via decoupled look-back over t-segments.
// Because every segment has fixed length TW=24, the segment's affine EMA map
// m' = A*m + B has a COMPILE-TIME A = 0.99^24. Blocks publish only their local
// aggregate B (one float, packed with a status bit into a 64-bit word, single
// release-store). A block's inflow mean is a pure sum over predecessors'
// aggregates weighted by A^k — no inclusive chain, no serial look-back.
// mag is read once (held in registers) and written once. Flags (32 KB) live
// in d_ws, zeroed by hipMemsetAsync each launch (graph-capturable).

#define B_    32
#define F_    257
#define T_    3000
#define T4    750          // float4s per row
#define TW    24           // t-window per block (3000 = 125 * 24)
#define SL    6            // float4 slots per segment (TW/4)
#define NSEG  125          // segments per batch; grid = B_*NSEG = 4000
#define NG    42           // f-groups: tid/SL; 42*6 = 252 active threads
#define MOM   0.99f
#define OMM   0.01f
#define EPS_  1e-8f
#define INVF  (1.0f / 257.0f)

__global__ __launch_bounds__(256) void ema_fused(
    const float* __restrict__ mag,
    const float* __restrict__ bias,
    const float* __restrict__ rmean,
    float* __restrict__ out,
    float* __restrict__ mag_mean,
    unsigned long long* __restrict__ flags)
{
    __shared__ float  red[NG][TW];      // per-group partial sums, t-major (4032 B)
    __shared__ float  fs[TW];           // frame means for this segment
    __shared__ float4 rec4[SL];         // 1/(mean+bias+eps), per float4 slot
    __shared__ float4 mwb4[SL];         // mean+bias (mag_mean payload)
    __shared__ float  powA[NSEG + 1];   // A_seg^l, l = 0..125

    const int blk  = blockIdx.x;        // b*NSEG + s
    const int b    = blk / NSEG;
    const int s    = blk % NSEG;
    const int tid  = threadIdx.x;
    const int g    = tid / SL;          // f-group (0..41); g>=NG idle for loads
    const int slot = tid % SL;          // float4 slot in segment

    // A-power table, built by an idle thread concurrently with the loads.
    // A_seg built by 24 serial multiplies to mirror the reference's rounding.
    if (tid == 255) {
        float a = 1.f;
        #pragma unroll
        for (int i = 0; i < TW; ++i) a *= MOM;
        float p = 1.f;
        powA[0] = 1.f;
        for (int l = 1; l <= NSEG; ++l) { p *= a; powA[l] = p; }
    }

    // ---- phase 1: load 24-wide t-window of 6-7 f-rows into REGISTERS;
    //      per-thread partial sum over own rows -> LDS.
    float4 vals[7];
    if (g < NG) {
        const float4* magv = reinterpret_cast<const float4*>(mag);
        float4 a4 = make_float4(0.f, 0.f, 0.f, 0.f);
        int fi = g;
        #pragma unroll
        for (int r = 0; r < 7; ++r) {              // static indices (rule #20)
            if (fi < F_) {
                float4 v = magv[(size_t)(b * F_ + fi) * T4 + s * SL + slot];
                vals[r] = v;
                a4.x += v.x; a4.y += v.y; a4.z += v.z; a4.w += v.w;
            }
            fi += NG;
        }
        red[g][slot * 4 + 0] = a4.x;
        red[g][slot * 4 + 1] = a4.y;
        red[g][slot * 4 + 2] = a4.z;
        red[g][slot * 4 + 3] = a4.w;
    }
    __syncthreads();

    // ---- phase 2: finish F-reduction -> frame means (24 lanes, conflict-free:
    //      bank = (gg*24 + tid) % 32, distinct across the 24 lanes)
    if (tid < TW) {
        float sum = 0.f;
        #pragma unroll
        for (int gg = 0; gg < NG; ++gg) sum += red[gg][tid];
        fs[tid] = sum * INVF;
    }
    __syncthreads();

    // ---- phase 3a: local affine aggregate B, publish immediately (release).
    if (tid == 0) {
        float Bv = 0.f;
        #pragma unroll
        for (int i = 0; i < TW; ++i) Bv = MOM * Bv + OMM * fs[i];
        unsigned long long st =
            (1ull << 32) | (unsigned long long)__float_as_uint(Bv);
        __hip_atomic_store(&flags[blk], st, __ATOMIC_RELEASE,
                           __HIP_MEMORY_SCOPE_AGENT);
    }

    // ---- phase 3b: parallel look-back over AGGREGATES ONLY (wave 0).
    //      lane l handles predecessor distance k = l+1 (and l+65 in round 2);
    //      m_in = sum_k A^(k-1)*B_{s-k} + A^s*rmean. No inclusive chain.
    if (tid < 64) {
        float term = 0.f;
        const unsigned long long* fb = flags + b * NSEG;
        const int k1 = tid + 1;
        if (k1 <= s) {
            unsigned long long st;
            do {
                st = __hip_atomic_load(&fb[s - k1], __ATOMIC_ACQUIRE,
                                       __HIP_MEMORY_SCOPE_AGENT);
                if (!(st >> 32)) __builtin_amdgcn_s_sleep(2);
            } while (!(st >> 32));
            term = powA[k1 - 1] * __uint_as_float((unsigned)st);
        }
        const int k2 = tid + 65;
        if (k2 <= s) {
            unsigned long long st;
            do {
                st = __hip_atomic_load(&fb[s - k2], __ATOMIC_ACQUIRE,
                                       __HIP_MEMORY_SCOPE_AGENT);
                if (!(st >> 32)) __builtin_amdgcn_s_sleep(2);
            } while (!(st >> 32));
            term += powA[k2 - 1] * __uint_as_float((unsigned)st);
        }
        if (tid == 0) term += powA[s] * rmean[0];
        #pragma unroll
        for (int off = 32; off > 0; off >>= 1)
            term += __shfl_down(term, off);

        // lane 0: 24-step local scan -> mean+bias and reciprocals into LDS
        if (tid == 0) {
            const float b0 = bias[0];
            float m = term;                       // m_{t0-1}
            float* mwb = reinterpret_cast<float*>(mwb4);
            float* rc  = reinterpret_cast<float*>(rec4);
            #pragma unroll
            for (int i = 0; i < TW; ++i) {
                m = MOM * m + OMM * fs[i];
                const float mb = m + b0;
                mwb[i] = mb;
                rc[i]  = 1.0f / (mb + EPS_);
            }
        }
    }
    __syncthreads();

    // ---- phase 4: normalize FROM REGISTERS, write out; 6 lanes write mag_mean
    if (g < NG) {
        const float4 rr = rec4[slot];             // broadcast read, conflict-free
        float4* ov = reinterpret_cast<float4*>(out);
        int fi = g;
        #pragma unroll
        for (int r = 0; r < 7; ++r) {
            if (fi < F_) {
                float4 v = vals[r];
                float4 o;
                o.x = v.x * rr.x; o.y = v.y * rr.y;
                o.z = v.z * rr.z; o.w = v.w * rr.w;
                ov[(size_t)(b * F_ + fi) * T4 + s * SL + slot] = o;
            }
            fi += NG;
        }
    }
    if (tid < SL) {
        reinterpret_cast<float4*>(mag_mean)[b * T4 + s * SL + tid] = mwb4[tid];
    }
}

extern "C" void kernel_launch(void* const* d_in, const int* in_sizes, int n_in,
                              void* d_out, int out_size, void* d_ws, size_t ws_size,
                              hipStream_t stream) {
    (void)in_sizes; (void)n_in; (void)out_size; (void)ws_size;
    const float* mag   = (const float*)d_in[0];
    const float* bias  = (const float*)d_in[1];
    const float* rmean = (const float*)d_in[2];
    float* out      = (float*)d_out;
    float* mag_mean = out + (size_t)B_ * F_ * T_;          // second tuple output
    unsigned long long* flags = (unsigned long long*)d_ws; // 4000 * 8 B = 32 KB

    hipMemsetAsync(d_ws, 0, (size_t)B_ * NSEG * sizeof(unsigned long long), stream);
    ema_fused<<<B_ * NSEG, 256, 0, stream>>>(mag, bias, rmean, out, mag_mean, flags);
}

// Round 3
// 206.402 us; speedup vs baseline: 2.3509x; 2.3509x over previous
//
#include <hip/hip_runtime.h>

// EMA energy normalizer: mag [B,F,T] fp32 -> (mag_norm [B,F,T], mag_mean [B,1,T])
//
// R7 (resubmit — R2 bench was a broker timeout, no data): LINEAR-ACCESS
// 3-kernel pipeline. R6 evidence: perfect traffic (97+97 MB) but 564 GB/s —
// columnar gathers (96-480B runs at 12KB stride) run at ~0.6 TB/s on this
// part regardless of synchronization. Fix: every kernel walks full 12KB rows
// with wave-contiguous 1KB-per-instruction runs.
//   K1  (512 blocks):  16-17 full rows -> register-accumulated partial row.
//   KRS (32 blocks):   reduce partials (or mag directly if ws too small),
//                      Hillis-Steele affine scan (validated), write
//                      mag_mean + recip table (384 KB).
//   K3  (1056 blocks): recip row -> LDS, stream 8 rows: read*recip -> write.
// No atomics, no spins, no inter-block waits.

#define B_   32
#define F_   257
#define T_   3000
#define T4   750          // float4s per row
#define NG1  16           // f-groups in K1; g==15 takes 17 rows (16*16+1=257)
#define MOM  0.99f
#define OMM  0.01f
#define EPS_ 1e-8f
#define INVF (1.0f / 257.0f)

#define ACC4(a, v) { a.x += v.x; a.y += v.y; a.z += v.z; a.w += v.w; }

// ---------------------------------------------------------------------------
// K1: block (b, g) reduces rows [g*16, g*16+nr) of batch b into one partial
// row. Thread owns float4 columns {tid, tid+256, tid+512}; every load is a
// wave-contiguous 1 KB run; rows are read fully linearly.
// ---------------------------------------------------------------------------
__global__ __launch_bounds__(256) void k1_partial(const float* __restrict__ mag,
                                                  float* __restrict__ partial) {
    const int blk = blockIdx.x;          // b*16 + g
    const int b   = blk >> 4;
    const int g   = blk & 15;
    const int tid = threadIdx.x;
    const bool has2 = tid < (T4 - 512);  // tid < 238 owns a third column

    const float4* magv = reinterpret_cast<const float4*>(mag)
                       + ((size_t)(b * F_ + g * 16)) * T4;
    float4 a0 = make_float4(0.f,0.f,0.f,0.f);
    float4 a1 = make_float4(0.f,0.f,0.f,0.f);
    float4 a2 = make_float4(0.f,0.f,0.f,0.f);

    #pragma unroll 4
    for (int r = 0; r < 16; ++r) {
        const float4* row = magv + (size_t)r * T4;
        float4 v0 = row[tid];
        float4 v1 = row[tid + 256];
        ACC4(a0, v0);
        ACC4(a1, v1);
        if (has2) { float4 v2 = row[tid + 512]; ACC4(a2, v2); }
    }
    if (g == 15) {                       // row 256 (the odd one out)
        const float4* row = magv + (size_t)16 * T4;
        float4 v0 = row[tid];
        float4 v1 = row[tid + 256];
        ACC4(a0, v0);
        ACC4(a1, v1);
        if (has2) { float4 v2 = row[tid + 512]; ACC4(a2, v2); }
    }

    float4* pv = reinterpret_cast<float4*>(partial) + (size_t)blk * T4;
    pv[tid]       = a0;
    pv[tid + 256] = a1;
    if (has2) pv[tid + 512] = a2;
}

// ---------------------------------------------------------------------------
// KRS: one block per batch. Reduce nrows rows of src (partial: nrows=16, or
// mag directly: nrows=257) -> frame means in LDS -> affine Hillis-Steele scan
// (m' = A*m + B) -> write mag_mean (mean+bias) and recip (1/(mean+bias+eps)).
// ---------------------------------------------------------------------------
__global__ __launch_bounds__(256) void k_reduce_scan(const float* __restrict__ src,
                                                     int nrows,
                                                     const float* __restrict__ bias,
                                                     const float* __restrict__ rmean,
                                                     float* __restrict__ recip,
                                                     float* __restrict__ mag_mean) {
    __shared__ float4 xs4[T4];           // 12 KB frame means
    float* xs = reinterpret_cast<float*>(xs4);
    __shared__ float sA[256];
    __shared__ float sB[256];

    const int b   = blockIdx.x;
    const int tid = threadIdx.x;
    const bool has2 = tid < (T4 - 512);

    // ---- column reduction over nrows rows
    {
        const float4* sv = reinterpret_cast<const float4*>(src)
                         + (size_t)b * nrows * T4;
        float4 a0 = make_float4(0.f,0.f,0.f,0.f);
        float4 a1 = make_float4(0.f,0.f,0.f,0.f);
        float4 a2 = make_float4(0.f,0.f,0.f,0.f);
        #pragma unroll 4
        for (int r = 0; r < nrows; ++r) {
            const float4* row = sv + (size_t)r * T4;
            float4 v0 = row[tid];
            float4 v1 = row[tid + 256];
            ACC4(a0, v0);
            ACC4(a1, v1);
            if (has2) { float4 v2 = row[tid + 512]; ACC4(a2, v2); }
        }
        a0.x *= INVF; a0.y *= INVF; a0.z *= INVF; a0.w *= INVF;
        a1.x *= INVF; a1.y *= INVF; a1.z *= INVF; a1.w *= INVF;
        xs4[tid]       = a0;
        xs4[tid + 256] = a1;
        if (has2) {
            a2.x *= INVF; a2.y *= INVF; a2.z *= INVF; a2.w *= INVF;
            xs4[tid + 512] = a2;
        }
    }
    __syncthreads();

    // ---- local chunk scan: 250 active threads x 12 steps (validated R5 code)
    const int CH = 12;
    const int t0 = tid * CH;
    float A = 1.f, Bv = 0.f;
    if (t0 < T_) {
        #pragma unroll
        for (int j = 0; j < CH; ++j) {
            Bv = MOM * Bv + OMM * xs[t0 + j];
            A *= MOM;
        }
    }
    sA[tid] = A; sB[tid] = Bv;
    __syncthreads();

    // Hillis-Steele over affine maps: (Ap,Bp)∘(Ac,Bc) = (Ap*Ac, Bp*Ac+Bc)
    for (int off = 1; off < 256; off <<= 1) {
        float cA = sA[tid], cB = sB[tid];
        float pA = 1.f, pB = 0.f;
        if (tid >= off) { pA = sA[tid - off]; pB = sB[tid - off]; }
        __syncthreads();
        if (tid >= off) { sA[tid] = pA * cA; sB[tid] = pB * cA + cB; }
        __syncthreads();
    }

    float pA = 1.f, pB = 0.f;
    if (tid > 0) { pA = sA[tid - 1]; pB = sB[tid - 1]; }
    __syncthreads();

    const float bias0 = bias[0];
    if (t0 < T_) {
        float m = pA * rmean[0] + pB;        // m_{t0-1}
        #pragma unroll
        for (int j = 0; j < CH; ++j) {
            m = MOM * m + OMM * xs[t0 + j];
            xs[t0 + j] = m + bias0;          // mean + bias
        }
    }
    __syncthreads();

    // ---- emit mag_mean and reciprocal table
    float4* mmv = reinterpret_cast<float4*>(mag_mean) + (size_t)b * T4;
    float4* rcv = reinterpret_cast<float4*>(recip)    + (size_t)b * T4;
    for (int i = tid; i < T4; i += 256) {
        float4 v = xs4[i];
        mmv[i] = v;
        float4 rv;
        rv.x = 1.0f / (v.x + EPS_); rv.y = 1.0f / (v.y + EPS_);
        rv.z = 1.0f / (v.z + EPS_); rv.w = 1.0f / (v.w + EPS_);
        rcv[i] = rv;
    }
}

// ---------------------------------------------------------------------------
// K3: block (b, ch) normalizes rows [ch*8, ch*8+nr). recip row staged in LDS,
// register-held per-column recips, fully linear row reads/writes.
// ---------------------------------------------------------------------------
__global__ __launch_bounds__(256) void k3_norm(const float* __restrict__ mag,
                                               const float* __restrict__ recip,
                                               float* __restrict__ out) {
    __shared__ float4 rec4[T4];          // 12 KB
    const int blk = blockIdx.x;          // b*33 + ch
    const int b   = blk / 33;
    const int ch  = blk % 33;
    const int tid = threadIdx.x;

    {
        const float4* rcv = reinterpret_cast<const float4*>(recip) + (size_t)b * T4;
        for (int i = tid; i < T4; i += 256) rec4[i] = rcv[i];
    }
    __syncthreads();

    const bool has2 = tid < (T4 - 512);
    const float4 r0 = rec4[tid];
    const float4 r1 = rec4[tid + 256];
    const float4 r2 = has2 ? rec4[tid + 512] : r0;

    const int f0 = ch * 8;
    const int nr = (ch == 32) ? 1 : 8;
    const float4* magv = reinterpret_cast<const float4*>(mag)
                       + ((size_t)(b * F_ + f0)) * T4;
    float4* ov = reinterpret_cast<float4*>(out)
               + ((size_t)(b * F_ + f0)) * T4;

    for (int r = 0; r < nr; ++r) {
        const float4* row = magv + (size_t)r * T4;
        float4*       orow = ov  + (size_t)r * T4;
        float4 v0 = row[tid];
        float4 v1 = row[tid + 256];
        float4 o;
        o.x = v0.x * r0.x; o.y = v0.y * r0.y; o.z = v0.z * r0.z; o.w = v0.w * r0.w;
        orow[tid] = o;
        o.x = v1.x * r1.x; o.y = v1.y * r1.y; o.z = v1.z * r1.z; o.w = v1.w * r1.w;
        orow[tid + 256] = o;
        if (has2) {
            float4 v2 = row[tid + 512];
            o.x = v2.x * r2.x; o.y = v2.y * r2.y; o.z = v2.z * r2.z; o.w = v2.w * r2.w;
            orow[tid + 512] = o;
        }
    }
}

extern "C" void kernel_launch(void* const* d_in, const int* in_sizes, int n_in,
                              void* d_out, int out_size, void* d_ws, size_t ws_size,
                              hipStream_t stream) {
    (void)in_sizes; (void)n_in; (void)out_size;
    const float* mag   = (const float*)d_in[0];
    const float* bias  = (const float*)d_in[1];
    const float* rmean = (const float*)d_in[2];
    float* out      = (float*)d_out;
    float* mag_mean = out + (size_t)B_ * F_ * T_;       // second tuple output

    float* recip = (float*)d_ws;                        // 384 KB
    const size_t recip_sz   = (size_t)B_ * T_ * sizeof(float);
    const size_t partial_sz = (size_t)B_ * NG1 * T_ * sizeof(float);  // 6.14 MB

    if (ws_size >= recip_sz + partial_sz) {
        // Path A: two-stage reduction, all-linear reads.
        float* partial = recip + (size_t)B_ * T_;
        k1_partial<<<B_ * NG1, 256, 0, stream>>>(mag, partial);
        k_reduce_scan<<<B_, 256, 0, stream>>>(partial, NG1, bias, rmean,
                                              recip, mag_mean);
    } else {
        // Path B: reduce mag directly (32 fat blocks), needs only 384 KB ws.
        k_reduce_scan<<<B_, 256, 0, stream>>>(mag, F_, bias, rmean,
                                              recip, mag_mean);
    }
    k3_norm<<<B_ * 33, 256, 0, stream>>>(mag, recip, out);
}